// Round 1
// baseline (166.717 us; speedup 1.0000x reference)
//
#include <hip/hip_runtime.h>
#include <math.h>

#define N_ 16
#define C_ 4
#define F_ 257
#define T_ 1000
#define TP_ 1024   // padded T stride for the mag intermediate
#define B_ 8
#define K_ 80
#define BK_ (B_*K_)   // 640

static __device__ __forceinline__ float relu_log(float v) {
    v = fmaxf(v, 0.0f);
    return logf(v + 1e-5f);
}

// ---------------- kernel 1: beamform + magnitude ----------------
// grid: N_*F_ blocks, 256 threads. Each block: fixed (n, f), all b, loop over t.
__global__ __launch_bounds__(256) void k_beamform(
    const float* __restrict__ xr, const float* __restrict__ xi,
    const float* __restrict__ wr, const float* __restrict__ wi,
    float* __restrict__ mag) {
    const int blk = blockIdx.x;
    const int f = blk % F_;
    const int n = blk / F_;

    float wrr[B_][C_], wii[B_][C_];
#pragma unroll
    for (int b = 0; b < B_; ++b)
#pragma unroll
        for (int c = 0; c < C_; ++c) {
            wrr[b][c] = wr[(f * B_ + b) * C_ + c];
            wii[b][c] = wi[(f * B_ + b) * C_ + c];
        }

    const float* xr0 = xr + (size_t)n * C_ * F_ * T_ + (size_t)f * T_;
    const float* xi0 = xi + (size_t)n * C_ * F_ * T_ + (size_t)f * T_;
    float* mag0 = mag + ((size_t)(n * B_) * F_ + f) * TP_;

    for (int t = threadIdx.x; t < TP_; t += 256) {
        if (t < T_) {
            float xrv[C_], xiv[C_];
#pragma unroll
            for (int c = 0; c < C_; ++c) {
                xrv[c] = xr0[(size_t)c * F_ * T_ + t];
                xiv[c] = xi0[(size_t)c * F_ * T_ + t];
            }
#pragma unroll
            for (int b = 0; b < B_; ++b) {
                float br = 0.f, bi = 0.f;
#pragma unroll
                for (int c = 0; c < C_; ++c) {
                    br += xrv[c] * wrr[b][c];
                    br -= xiv[c] * wii[b][c];
                    bi += xiv[c] * wrr[b][c];
                    bi += xrv[c] * wii[b][c];
                }
                float m = sqrtf(br * br + bi * bi + 1e-5f);
                mag0[(size_t)b * F_ * TP_ + t] = m;
            }
        } else {
            // zero the pad columns so downstream reads are benign
#pragma unroll
            for (int b = 0; b < B_; ++b)
                mag0[(size_t)b * F_ * TP_ + t] = 0.f;
        }
    }
}

// ---------------- kernel 2: projection GEMM + relu + log + BN partial sums ----
// grid: N_*B_*16 blocks (16 t-tiles of 64), 256 threads.
// thread: kx = tid&15 -> k base kx*5 (5 k's), ty = tid>>4 -> t base ty*4 (4 t's)
__global__ __launch_bounds__(256) void k_proj(
    const float* __restrict__ mag, const float* __restrict__ w_proj,
    float* __restrict__ out, double* __restrict__ sums) {
    const int bid = blockIdx.x;
    const int tt = bid & 15;
    const int b = (bid >> 4) & 7;
    const int n = bid >> 7;
    const int t0 = tt * 64;

    const int tid = threadIdx.x;
    const int kx = tid & 15;
    const int ty = tid >> 4;
    const int kb = kx * 5;

    __shared__ float magS[32][64];
    __shared__ float wS[32][81];

    float acc[5][4];
#pragma unroll
    for (int j = 0; j < 5; ++j)
#pragma unroll
        for (int i = 0; i < 4; ++i) acc[j][i] = 0.f;

    const float* magNB = mag + ((size_t)(n * B_ + b) * F_) * TP_;

    for (int ch = 0; ch < 8; ++ch) {
        const int f0 = ch * 32;
        // stage mag chunk: 32 f-rows x 64 t  (512 float4 loads)
#pragma unroll
        for (int r = 0; r < 2; ++r) {
            int idx = tid + r * 256;
            int row = idx >> 4, c4 = idx & 15;
            float4 v = *(const float4*)(magNB + (size_t)(f0 + row) * TP_ + t0 + c4 * 4);
            *(float4*)&magS[row][c4 * 4] = v;
        }
        // stage w chunk: 80 k x 32 f, transposed to wS[f][k]
#pragma unroll
        for (int r = 0; r < 10; ++r) {
            int idx = tid + r * 256;
            int k = idx >> 5, fc = idx & 31;
            wS[fc][k] = w_proj[k * F_ + f0 + fc];
        }
        __syncthreads();
#pragma unroll 8
        for (int fc = 0; fc < 32; ++fc) {
            float4 m = *(const float4*)&magS[fc][ty * 4];
#pragma unroll
            for (int j = 0; j < 5; ++j) {
                float w = wS[fc][kb + j];
                acc[j][0] += w * m.x;
                acc[j][1] += w * m.y;
                acc[j][2] += w * m.z;
                acc[j][3] += w * m.w;
            }
        }
        __syncthreads();
    }
    // tail f = 256
    {
        float4 m = *(const float4*)(magNB + (size_t)256 * TP_ + t0 + ty * 4);
#pragma unroll
        for (int j = 0; j < 5; ++j) {
            float w = w_proj[(kb + j) * F_ + 256];
            acc[j][0] += w * m.x;
            acc[j][1] += w * m.y;
            acc[j][2] += w * m.z;
            acc[j][3] += w * m.w;
        }
    }

    // epilogue: relu+log, store, BN partial sums
    double s1 = 0.0, s2 = 0.0;
#pragma unroll
    for (int i = 0; i < 4; ++i) {
        int t = t0 + ty * 4 + i;
        if (t < T_) {
            float* orow = out + ((size_t)n * T_ + t) * BK_ + b * K_ + kb;
#pragma unroll
            for (int j = 0; j < 5; ++j) {
                float v = relu_log(acc[j][i]);
                orow[j] = v;
                s1 += (double)v;
                s2 += (double)v * (double)v;
            }
        }
    }
    // wave reduce (wave64)
#pragma unroll
    for (int off = 32; off; off >>= 1) {
        s1 += __shfl_down(s1, off);
        s2 += __shfl_down(s2, off);
    }
    __shared__ double red1[4], red2[4];
    int wid = tid >> 6, lane = tid & 63;
    if (lane == 0) { red1[wid] = s1; red2[wid] = s2; }
    __syncthreads();
    if (tid == 0) {
        double a1 = red1[0] + red1[1] + red1[2] + red1[3];
        double a2 = red2[0] + red2[1] + red2[2] + red2[3];
        atomicAdd(&sums[b], a1);
        atomicAdd(&sums[B_ + b], a2);
    }
}

// ---------------- kernel 3a: per-channel scale/shift from sums ----------------
__global__ void k_bnstats(const double* __restrict__ sums,
                          const float* __restrict__ gamma,
                          const float* __restrict__ beta,
                          float* __restrict__ ss) {
    int b = threadIdx.x;
    if (b < B_) {
        const double cnt = (double)N_ * T_ * K_;
        double mean = sums[b] / cnt;
        double var = sums[B_ + b] / cnt - mean * mean;
        float scale = gamma[b] * (float)(1.0 / sqrt(var + 1e-5));
        float shift = beta[b] - (float)mean * scale;
        ss[b] = scale;
        ss[B_ + b] = shift;
    }
}

// ---------------- kernel 3b: apply BN in place over d_out ----------------
// 10,240,000 floats = 2,560,000 float4; grid 10000 x 256
__global__ __launch_bounds__(256) void k_bnapply(float* __restrict__ out,
                                                 const float* __restrict__ ss) {
    size_t i4 = (size_t)blockIdx.x * 256 + threadIdx.x;
    int k4 = (int)(i4 % (BK_ / 4));  // 160 float4 per (n,t) row
    int b = k4 / (K_ / 4);           // 20 float4 per channel
    float scale = ss[b], shift = ss[B_ + b];
    float4* p = (float4*)out + i4;
    float4 v = *p;
    v.x = v.x * scale + shift;
    v.y = v.y * scale + shift;
    v.z = v.z * scale + shift;
    v.w = v.w * scale + shift;
    *p = v;
}

extern "C" void kernel_launch(void* const* d_in, const int* in_sizes, int n_in,
                              void* d_out, int out_size, void* d_ws, size_t ws_size,
                              hipStream_t stream) {
    const float* xr = (const float*)d_in[0];
    const float* xi = (const float*)d_in[1];
    const float* wr = (const float*)d_in[2];
    const float* wi = (const float*)d_in[3];
    const float* w_proj = (const float*)d_in[4];
    const float* gamma = (const float*)d_in[5];
    const float* beta = (const float*)d_in[6];
    float* out = (float*)d_out;

    double* sums = (double*)d_ws;                      // 16 doubles
    float* ss = (float*)((char*)d_ws + 128);           // 16 floats
    float* mag = (float*)((char*)d_ws + 512);          // N*B*F*TP floats

    hipMemsetAsync(d_ws, 0, 512, stream);
    k_beamform<<<N_ * F_, 256, 0, stream>>>(xr, xi, wr, wi, mag);
    k_proj<<<N_ * B_ * 16, 256, 0, stream>>>(mag, w_proj, out, sums);
    k_bnstats<<<1, 64, 0, stream>>>(sums, gamma, beta, ss);
    k_bnapply<<<10000, 256, 0, stream>>>(out, ss);
}